// Round 9
// baseline (566.262 us; speedup 1.0000x reference)
//
#include <hip/hip_runtime.h>
#include <hip/hip_fp16.h>

#define N_NODES 50000
#define N_EDGES 800000
#define D 128
#define N_GRAPHS 64
#define NEG_SLOPE 0.01f
#define POOL_PARTS 8
#define ELLW 64   // max in-degree capacity; Poisson(16) over 50k nodes maxes ~42

// ---------------- ELL build (both branches), 4 edges/thread, ushort entries ----------------
#define FILL_T 200000  // N_EDGES/4
__global__ __launch_bounds__(256) void k_fill(const int* __restrict__ src0, const int* __restrict__ dst0,
                                              const int* __restrict__ src1, const int* __restrict__ dst1,
                                              int* __restrict__ cnti, unsigned short* __restrict__ ell0,
                                              unsigned short* __restrict__ ell1) {
    int br = blockIdx.y;
    const int* __restrict__ src = br ? src1 : src0;
    const int* __restrict__ dst = br ? dst1 : dst0;
    int* __restrict__ cnt = cnti + br * N_NODES;
    unsigned short* __restrict__ ell = br ? ell1 : ell0;
    int t = blockIdx.x * 256 + threadIdx.x;
    if (t >= FILL_T) return;
    int d_[4], s_[4];
#pragma unroll
    for (int k = 0; k < 4; k++) {
        d_[k] = dst[t + k * FILL_T];
        s_[k] = src[t + k * FILL_T];
    }
    int p_[4];
#pragma unroll
    for (int k = 0; k < 4; k++) p_[k] = atomicAdd(&cnt[d_[k]], 1);
#pragma unroll
    for (int k = 0; k < 4; k++)
        if (p_[k] < ELLW) ell[(size_t)d_[k] * ELLW + p_[k]] = (unsigned short)s_[k];
}

// ---------------- GEMM (both branches): Hs[N,128](fp16) = (x @ W) * rsqrt(cnt+1) ----------------
#define BM 64
#define BK 32
#define XSTRIDE 36
__global__ __launch_bounds__(256) void k_gemm(const float* __restrict__ x0, const float* __restrict__ x1,
                                              const float* __restrict__ Wa, const float* __restrict__ Wb,
                                              const int* __restrict__ cnti,
                                              __half* __restrict__ h0, __half* __restrict__ h1) {
    int br = blockIdx.y;
    const float* __restrict__ x = br ? x1 : x0;
    const float* __restrict__ W = br ? Wb : Wa;
    const int* __restrict__ cnt = cnti + br * N_NODES;
    __half* __restrict__ h = br ? h1 : h0;

    __shared__ float Xl[BM * XSTRIDE];
    __shared__ float Wl[BK * D];
    const int tid = threadIdx.x;
    const int row0 = blockIdx.x * BM;
    const int ty4 = (tid >> 4) * 4;
    const int tx4 = (tid & 15) * 4;

    float2 acc[4][4];
#pragma unroll
    for (int r = 0; r < 4; r++)
#pragma unroll
        for (int c = 0; c < 4; c++) acc[r][c] = make_float2(0.f, 0.f);

    for (int kb = 0; kb < D; kb += BK) {
#pragma unroll
        for (int i = 0; i < 2; i++) {
            int i2 = tid + 256 * i;
            int r = i2 >> 3, kg = i2 & 7;
            float4 xv = make_float4(0.f, 0.f, 0.f, 0.f);
            if (row0 + r < N_NODES) xv = *(const float4*)(x + (size_t)(row0 + r) * D + kb + kg * 4);
            *(float4*)&Xl[r * XSTRIDE + kg * 4] = xv;
        }
#pragma unroll
        for (int i = 0; i < 4; i++) {
            int i2 = tid + 256 * i;
            ((float4*)Wl)[i2] = ((const float4*)W)[(size_t)kb * 32 + i2];
        }
        __syncthreads();
#pragma unroll
        for (int k4 = 0; k4 < BK; k4 += 4) {
            float a_[4][4];
#pragma unroll
            for (int r = 0; r < 4; r++) {
                float4 t = *(const float4*)&Xl[(ty4 + r) * XSTRIDE + k4];
                a_[r][0] = t.x; a_[r][1] = t.y; a_[r][2] = t.z; a_[r][3] = t.w;
            }
#pragma unroll
            for (int kk = 0; kk < 4; kk++) {
                float4 b0 = *(const float4*)&Wl[(k4 + kk) * D + tx4];
                float4 b1 = *(const float4*)&Wl[(k4 + kk) * D + tx4 + 64];
                float bv[8] = {b0.x, b0.y, b0.z, b0.w, b1.x, b1.y, b1.z, b1.w};
#pragma unroll
                for (int r = 0; r < 4; r++)
#pragma unroll
                    for (int c = 0; c < 4; c++) {
                        acc[r][c].x = fmaf(a_[r][kk], bv[c], acc[r][c].x);
                        acc[r][c].y = fmaf(a_[r][kk], bv[c + 4], acc[r][c].y);
                    }
            }
        }
        __syncthreads();
    }
    // acc[r][c].x -> column tx4+c ; acc[r][c].y -> column tx4+64+c
#pragma unroll
    for (int r = 0; r < 4; r++) {
        int row = row0 + ty4 + r;
        if (row < N_NODES) {
            float di = rsqrtf((float)cnt[row] + 1.0f);
            union { __half2 h2[2]; float2 f2; } u0, u1;
            u0.h2[0] = __floats2half2_rn(acc[r][0].x * di, acc[r][1].x * di);
            u0.h2[1] = __floats2half2_rn(acc[r][2].x * di, acc[r][3].x * di);
            u1.h2[0] = __floats2half2_rn(acc[r][0].y * di, acc[r][1].y * di);
            u1.h2[1] = __floats2half2_rn(acc[r][2].y * di, acc[r][3].y * di);
            *(float2*)(h + (size_t)row * D + tx4) = u0.f2;
            *(float2*)(h + (size_t)row * D + tx4 + 64) = u1.f2;
        }
    }
}

// ---------------- ELL aggregation (both branches): one wave per dst node ----------------
__global__ __launch_bounds__(256) void k_agg(const int* __restrict__ cnti,
                                             const unsigned short* __restrict__ ell0,
                                             const unsigned short* __restrict__ ell1,
                                             const __half* __restrict__ Hs0, const __half* __restrict__ Hs1,
                                             const float* __restrict__ bias0, const float* __restrict__ bias1,
                                             float* __restrict__ out0, float* __restrict__ out1) {
    int br = blockIdx.y;
    const int* __restrict__ cnt = cnti + br * N_NODES;
    const unsigned short* __restrict__ ell = br ? ell1 : ell0;
    const __half2* __restrict__ H2 = (const __half2*)(br ? Hs1 : Hs0);
    const float* __restrict__ bias = br ? bias1 : bias0;
    float* __restrict__ out = br ? out1 : out0;

    int lane = threadIdx.x & 63;
    int node = __builtin_amdgcn_readfirstlane(blockIdx.x * 4 + (threadIdx.x >> 6));
    int n = cnt[node];
    const unsigned short* __restrict__ ep = ell + (size_t)node * ELLW;
    float2 acc[8];
    acc[0] = __half22float2(H2[(size_t)node * 64 + lane]);  // self term (already dinv-scaled)
#pragma unroll
    for (int i = 1; i < 8; i++) acc[i] = make_float2(0.f, 0.f);
    for (int j = 0; j < n; j += 8) {
        int s[8]; float w[8];
#pragma unroll
        for (int i = 0; i < 8; i++) {
            bool v = (j + i) < n;
            s[i] = v ? (int)ep[j + i] : 0;
            w[i] = v ? 1.0f : 0.0f;
        }
#pragma unroll
        for (int i = 0; i < 8; i++) {
            float2 hv = __half22float2(H2[(size_t)s[i] * 64 + lane]);
            acc[i].x = fmaf(w[i], hv.x, acc[i].x);
            acc[i].y = fmaf(w[i], hv.y, acc[i].y);
        }
    }
    float sx = ((acc[0].x + acc[1].x) + (acc[2].x + acc[3].x)) + ((acc[4].x + acc[5].x) + (acc[6].x + acc[7].x));
    float sy = ((acc[0].y + acc[1].y) + (acc[2].y + acc[3].y)) + ((acc[4].y + acc[5].y) + (acc[6].y + acc[7].y));
    float di = rsqrtf((float)n + 1.0f);
    float2 b = ((const float2*)bias)[lane];
    float vx = sx * di + b.x;
    float vy = sy * di + b.y;
    vx = vx > 0.0f ? vx : NEG_SLOPE * vx;
    vy = vy > 0.0f ? vy : NEG_SLOPE * vy;
    float2 r; r.x = vx; r.y = vy;
    ((float2*)out)[(size_t)node * 64 + lane] = r;
}

// ---------------- mean pool (both branches): per-(graph,part) partials ----------------
__device__ __forceinline__ int lower_bound_i(const int* __restrict__ arr, int n, int key) {
    int lo = 0, hi = n;
    while (lo < hi) {
        int mid = (lo + hi) >> 1;
        if (arr[mid] < key) lo = mid + 1; else hi = mid;
    }
    return lo;
}

__global__ __launch_bounds__(256) void k_pool(const float* __restrict__ h0, const float* __restrict__ h1,
                                              const int* __restrict__ batch0, const int* __restrict__ batch1,
                                              float* __restrict__ pp0, float* __restrict__ pp1,
                                              float* __restrict__ cnt0, float* __restrict__ cnt1) {
    int br = blockIdx.z;
    const float* __restrict__ h = br ? h1 : h0;
    const int* __restrict__ batch = br ? batch1 : batch0;
    float* __restrict__ pp = br ? pp1 : pp0;
    float* __restrict__ cnt = br ? cnt1 : cnt0;

    int g = blockIdx.x;
    int part = blockIdx.y;
    int lo = lower_bound_i(batch, N_NODES, g);
    int hi = lower_bound_i(batch, N_NODES, g + 1);
    int num = hi - lo;
    if (part == 0 && threadIdx.x == 0) cnt[g] = (float)num;
    int chunk = (num + POOL_PARTS - 1) / POOL_PARTS;
    int a = lo + part * chunk;
    int b = min(a + chunk, hi);
    int c = threadIdx.x & 127;
    int sub = threadIdx.x >> 7;
    float acc = 0.0f;
    for (int node = a + sub; node < b; node += 2) acc += h[(size_t)node * D + c];
    __shared__ float tmp[256];
    tmp[threadIdx.x] = acc;
    __syncthreads();
    if (sub == 0) pp[((size_t)g * POOL_PARTS + part) * D + c] = tmp[threadIdx.x] + tmp[threadIdx.x + 128];
}

// ---------------- final MLP (reduces pool parts) ----------------
__global__ __launch_bounds__(128) void k_mlp(const float* __restrict__ pp1, const float* __restrict__ pp2,
                                             const float* __restrict__ cnt1, const float* __restrict__ cnt2,
                                             const float* __restrict__ lin1W, const float* __restrict__ lin1b,
                                             const float* __restrict__ lin2W, const float* __restrict__ lin2b,
                                             float* __restrict__ out) {
    int g = blockIdx.x;
    int c = threadIdx.x;
    __shared__ float cat[2 * D];
    float s1 = 0.f, s2 = 0.f;
#pragma unroll
    for (int p = 0; p < POOL_PARTS; p++) {
        s1 += pp1[((size_t)g * POOL_PARTS + p) * D + c];
        s2 += pp2[((size_t)g * POOL_PARTS + p) * D + c];
    }
    cat[c] = s1 / fmaxf(cnt1[g], 1.0f);
    cat[c + D] = s2 / fmaxf(cnt2[g], 1.0f);
    __syncthreads();
    float acc = lin1b[c];
#pragma unroll 8
    for (int k = 0; k < 2 * D; k++) acc += cat[k] * lin1W[k * D + c];
    acc = fmaxf(acc, 0.0f);
    float v = acc * lin2W[c];
#pragma unroll
    for (int off = 32; off > 0; off >>= 1) v += __shfl_down(v, off, 64);
    __shared__ float wsum[2];
    if ((c & 63) == 0) wsum[c >> 6] = v;
    __syncthreads();
    if (c == 0) out[g] = wsum[0] + wsum[1] + lin2b[0];
}

extern "C" void kernel_launch(void* const* d_in, const int* in_sizes, int n_in,
                              void* d_out, int out_size, void* d_ws, size_t ws_size,
                              hipStream_t stream) {
    const float* x1 = (const float*)d_in[0];
    const int*   e1 = (const int*)d_in[1];
    const int*   batch1 = (const int*)d_in[2];
    const float* x2 = (const float*)d_in[3];
    const int*   e2 = (const int*)d_in[4];
    const int*   batch2 = (const int*)d_in[5];
    const float* W1_0 = (const float*)d_in[6];
    const float* b1_0 = (const float*)d_in[7];
    const float* W1_1 = (const float*)d_in[8];
    const float* b1_1 = (const float*)d_in[9];
    const float* W2_0 = (const float*)d_in[10];
    const float* b2_0 = (const float*)d_in[11];
    const float* W2_1 = (const float*)d_in[12];
    const float* b2_1 = (const float*)d_in[13];
    const float* lin1W = (const float*)d_in[14];
    const float* lin1b = (const float*)d_in[15];
    const float* lin2W = (const float*)d_in[16];
    const float* lin2b = (const float*)d_in[17];
    float* out = (float*)d_out;

    float* ws = (float*)d_ws;
    float*  ACT0 = ws;                                    // 6.4M floats
    float*  ACT1 = ACT0 + (size_t)N_NODES * D;            // 6.4M floats
    __half* H0   = (__half*)(ACT1 + (size_t)N_NODES * D); // 6.4M halves
    __half* H1   = H0 + (size_t)N_NODES * D;              // 6.4M halves
    int*    cnti = (int*)(H1 + (size_t)N_NODES * D);      // 2 x 50000 (contiguous; one memset)
    unsigned short* ell0 = (unsigned short*)(cnti + 2 * N_NODES);  // 3.2M ushorts
    unsigned short* ell1 = ell0 + (size_t)N_NODES * ELLW;          // 3.2M ushorts
    float*  pp1  = (float*)(ell1 + (size_t)N_NODES * ELLW);
    float*  pp2  = pp1 + (size_t)N_GRAPHS * POOL_PARTS * D;
    float*  cnt1 = pp2 + (size_t)N_GRAPHS * POOL_PARTS * D;
    float*  cnt2 = cnt1 + N_GRAPHS;

    dim3 b256(256);
    int fillBlocks = (FILL_T + 255) / 256;
    int gemmBlocks = (N_NODES + BM - 1) / BM;  // 782
    int aggBlocks  = N_NODES / 4;              // 12500

    hipMemsetAsync(cnti, 0, 2 * N_NODES * sizeof(int), stream);
    k_fill<<<dim3(fillBlocks, 2), b256, 0, stream>>>(e1, e1 + N_EDGES, e2, e2 + N_EDGES, cnti, ell0, ell1);

    // layer 0
    k_gemm<<<dim3(gemmBlocks, 2), b256, 0, stream>>>(x1, x2, W1_0, W2_0, cnti, H0, H1);
    k_agg<<<dim3(aggBlocks, 2), b256, 0, stream>>>(cnti, ell0, ell1, H0, H1, b1_0, b2_0, ACT0, ACT1);
    // layer 1
    k_gemm<<<dim3(gemmBlocks, 2), b256, 0, stream>>>(ACT0, ACT1, W1_1, W2_1, cnti, H0, H1);
    k_agg<<<dim3(aggBlocks, 2), b256, 0, stream>>>(cnti, ell0, ell1, H0, H1, b1_1, b2_1, ACT0, ACT1);

    k_pool<<<dim3(N_GRAPHS, POOL_PARTS, 2), b256, 0, stream>>>(ACT0, ACT1, batch1, batch2, pp1, pp2, cnt1, cnt2);
    k_mlp<<<N_GRAPHS, dim3(128), 0, stream>>>(pp1, pp2, cnt1, cnt2, lin1W, lin1b, lin2W, lin2b, out);
}